// Round 3
// baseline (223.998 us; speedup 1.0000x reference)
//
#include <hip/hip_runtime.h>

// MFELoss: fused softmax(C=4) + masked-mean reduction to a scalar.
// R3: 16 rows/thread (32 loads in flight -> 2x MLP vs R2), per-wave partials
// written directly (no LDS/syncthreads tail), tiny finalize kernel.
// Note: ~138 us of the reported dur_us is harness restore/poison overhead
// (512 MiB d_ws fill @ 79 us + d_in restore) -- not controllable here.

#define BLOCK 256
#define ROWS 16

__device__ __forceinline__ void mfe_row(float4 x, int t, int o,
                                        float& fne_acc, float& fpe_acc,
                                        float& cnt_acc) {
    float m = fmaxf(fmaxf(x.x, x.y), fmaxf(x.z, x.w));
    float e0 = __expf(x.x - m);
    float e1 = __expf(x.y - m);
    float e2 = __expf(x.z - m);
    float e3 = __expf(x.w - m);
    float S = (e0 + e1) + (e2 + e3);
    float r = 1.0f / S;
    float p0 = e0 * r, p1 = e1 * r, p2 = e2 * r, p3 = e3 * r;
    float s = ((p0 + p1) + p2) + p3;          // ~1.0, computed faithfully
    float po = (o == 0) ? p0 : (o == 1) ? p1 : (o == 2) ? p2 : p3;

    float d1 = s - po;
    float d2 = po - 1.0f;
    float fne_i = 0.5f * (d1 * d1 + d2 * d2);
    float fpe_i = po * po;                    // 0.5*(po^2+po^2)

    bool is_o = (t == o);
    fne_acc += is_o ? fne_i : 0.0f;
    fpe_acc += is_o ? 0.0f : fpe_i;
    cnt_acc += is_o ? 1.0f : 0.0f;            // exact: per-wave count <= 1024 < 2^24
}

__global__ __launch_bounds__(BLOCK) void mfe_partial(
    const float4* __restrict__ preds,
    const int* __restrict__ target,
    const int* __restrict__ others_idx_p,
    float* __restrict__ fne_part,
    float* __restrict__ fpe_part,
    float* __restrict__ cnt_part,
    int n_rows)
{
    const int o = *others_idx_p;  // wave-uniform scalar
    int tid = blockIdx.x * blockDim.x + threadIdx.x;
    int nth = gridDim.x * blockDim.x;

    float fne_acc = 0.0f, fpe_acc = 0.0f, cnt_acc = 0.0f;

    if (tid + (ROWS - 1) * nth < n_rows) {
        // fast path: issue all 32 loads before any use -> deep MLP
        float4 x[ROWS];
        int    t[ROWS];
        #pragma unroll
        for (int k = 0; k < ROWS; ++k) x[k] = preds[tid + k * nth];
        #pragma unroll
        for (int k = 0; k < ROWS; ++k) t[k] = target[tid + k * nth];
        #pragma unroll
        for (int k = 0; k < ROWS; ++k)
            mfe_row(x[k], t[k], o, fne_acc, fpe_acc, cnt_acc);
    } else {
        for (int i = tid; i < n_rows; i += nth)
            mfe_row(preds[i], target[i], o, fne_acc, fpe_acc, cnt_acc);
    }

    // 64-lane wave reduction
    #pragma unroll
    for (int off = 32; off > 0; off >>= 1) {
        fne_acc += __shfl_down(fne_acc, off, 64);
        fpe_acc += __shfl_down(fpe_acc, off, 64);
        cnt_acc += __shfl_down(cnt_acc, off, 64);
    }

    // per-wave partials: no LDS round-trip, no __syncthreads tail
    if ((threadIdx.x & 63) == 0) {
        int part = blockIdx.x * (BLOCK / 64) + (threadIdx.x >> 6);
        fne_part[part] = fne_acc;
        fpe_part[part] = fpe_acc;
        cnt_part[part] = cnt_acc;
    }
}

__global__ __launch_bounds__(1024) void mfe_final(
    const float* __restrict__ fne_part,
    const float* __restrict__ fpe_part,
    const float* __restrict__ cnt_part,
    int nparts, int n_rows, float* __restrict__ out)
{
    double fn = 0.0, fp = 0.0, c = 0.0;
    for (int i = threadIdx.x; i < nparts; i += blockDim.x) {
        fn += (double)fne_part[i];
        fp += (double)fpe_part[i];
        c  += (double)cnt_part[i];
    }
    #pragma unroll
    for (int off = 32; off > 0; off >>= 1) {
        fn += __shfl_down(fn, off, 64);
        fp += __shfl_down(fp, off, 64);
        c  += __shfl_down(c, off, 64);
    }
    __shared__ double s_fn[16], s_fp[16], s_c[16];
    int wave = threadIdx.x >> 6;
    int lane = threadIdx.x & 63;
    if (lane == 0) { s_fn[wave] = fn; s_fp[wave] = fp; s_c[wave] = c; }
    __syncthreads();

    if (threadIdx.x == 0) {
        double tfn = 0.0, tfp = 0.0, tc = 0.0;
        int nwaves = blockDim.x >> 6;
        for (int w = 0; w < nwaves; ++w) { tfn += s_fn[w]; tfp += s_fp[w]; tc += s_c[w]; }
        double fne_num = tc;
        double fpe_num = (double)n_rows - fne_num;
        double res = 0.0;
        if (fpe_num > 0.0) res += tfp / fpe_num;
        if (fne_num > 0.0) res += tfn / fne_num;
        out[0] = (float)res;
    }
}

extern "C" void kernel_launch(void* const* d_in, const int* in_sizes, int n_in,
                              void* d_out, int out_size, void* d_ws, size_t ws_size,
                              hipStream_t stream) {
    const float4* preds = (const float4*)d_in[0];
    const int* target = (const int*)d_in[1];
    const int* others_idx = (const int*)d_in[2];
    float* out = (float*)d_out;

    int n_rows = in_sizes[0] / 4;   // B = 8388608

    int grid = (n_rows + BLOCK * ROWS - 1) / (BLOCK * ROWS);  // 2048 for B=2^23
    int nparts = grid * (BLOCK / 64);                          // per-wave partials

    // workspace layout: three float arrays of nparts
    float* fne_part = (float*)d_ws;
    float* fpe_part = fne_part + nparts;
    float* cnt_part = fpe_part + nparts;

    mfe_partial<<<grid, BLOCK, 0, stream>>>(preds, target, others_idx,
                                            fne_part, fpe_part, cnt_part, n_rows);
    mfe_final<<<1, 1024, 0, stream>>>(fne_part, fpe_part, cnt_part,
                                      nparts, n_rows, out);
}

// Round 4
// 222.398 us; speedup vs baseline: 1.0072x; 1.0072x over previous
//
#include <hip/hip_runtime.h>

// MFELoss: fused softmax(C=4) + masked-mean reduction to a scalar.
// R4: force real memory-level parallelism. R3 post-mortem showed VGPR=56 ->
// compiler collapsed the 32-load batch into a ~4-load sliding window (dur
// identical to R2). Here: 8 rows/thread, loads emitted pairwise (x[k],t[k])
// then __builtin_amdgcn_sched_barrier(0) pins all 16 VMEM ops before any
// compute, so each wave genuinely holds 16 outstanding loads.
// ~138 us of reported dur_us is fixed harness restore/poison overhead.

#define BLOCK 256
#define ROWS 8

__device__ __forceinline__ void mfe_row(float4 x, int t, int o,
                                        float& fne_acc, float& fpe_acc,
                                        float& cnt_acc) {
    float m = fmaxf(fmaxf(x.x, x.y), fmaxf(x.z, x.w));
    float e0 = __expf(x.x - m);
    float e1 = __expf(x.y - m);
    float e2 = __expf(x.z - m);
    float e3 = __expf(x.w - m);
    float S = (e0 + e1) + (e2 + e3);
    float r = 1.0f / S;
    float p0 = e0 * r, p1 = e1 * r, p2 = e2 * r, p3 = e3 * r;
    float s = ((p0 + p1) + p2) + p3;          // ~1.0, computed faithfully
    float po = (o == 0) ? p0 : (o == 1) ? p1 : (o == 2) ? p2 : p3;

    float d1 = s - po;
    float d2 = po - 1.0f;
    float fne_i = 0.5f * (d1 * d1 + d2 * d2);
    float fpe_i = po * po;                    // 0.5*(po^2+po^2)

    bool is_o = (t == o);
    fne_acc += is_o ? fne_i : 0.0f;
    fpe_acc += is_o ? 0.0f : fpe_i;
    cnt_acc += is_o ? 1.0f : 0.0f;            // exact in fp32 at these counts
}

__global__ __launch_bounds__(BLOCK) void mfe_partial(
    const float4* __restrict__ preds,
    const int* __restrict__ target,
    const int* __restrict__ others_idx_p,
    float* __restrict__ fne_part,
    float* __restrict__ fpe_part,
    float* __restrict__ cnt_part,
    int n_rows)
{
    const int o = *others_idx_p;  // wave-uniform scalar
    int tid = blockIdx.x * blockDim.x + threadIdx.x;
    int nth = gridDim.x * blockDim.x;

    float fne_acc = 0.0f, fpe_acc = 0.0f, cnt_acc = 0.0f;

    if (tid + (ROWS - 1) * nth < n_rows) {
        float4 x[ROWS];
        int    t[ROWS];
        // interleave x/t so the k-th row's compute only needs vmcnt<=2*(ROWS-1-k)
        #pragma unroll
        for (int k = 0; k < ROWS; ++k) {
            x[k] = preds[tid + k * nth];
            t[k] = target[tid + k * nth];
        }
        // hard scheduling fence: no compute may be hoisted above, no load may
        // sink below -> all 16 VMEM ops are genuinely in flight here.
        __builtin_amdgcn_sched_barrier(0);
        #pragma unroll
        for (int k = 0; k < ROWS; ++k)
            mfe_row(x[k], t[k], o, fne_acc, fpe_acc, cnt_acc);
    } else {
        for (int i = tid; i < n_rows; i += nth)
            mfe_row(preds[i], target[i], o, fne_acc, fpe_acc, cnt_acc);
    }

    // 64-lane wave reduction
    #pragma unroll
    for (int off = 32; off > 0; off >>= 1) {
        fne_acc += __shfl_down(fne_acc, off, 64);
        fpe_acc += __shfl_down(fpe_acc, off, 64);
        cnt_acc += __shfl_down(cnt_acc, off, 64);
    }

    // per-wave partials: no LDS round-trip, no __syncthreads tail
    if ((threadIdx.x & 63) == 0) {
        int part = blockIdx.x * (BLOCK / 64) + (threadIdx.x >> 6);
        fne_part[part] = fne_acc;
        fpe_part[part] = fpe_acc;
        cnt_part[part] = cnt_acc;
    }
}

__global__ __launch_bounds__(1024) void mfe_final(
    const float* __restrict__ fne_part,
    const float* __restrict__ fpe_part,
    const float* __restrict__ cnt_part,
    int nparts, int n_rows, float* __restrict__ out)
{
    double fn = 0.0, fp = 0.0, c = 0.0;
    for (int i = threadIdx.x; i < nparts; i += blockDim.x) {
        fn += (double)fne_part[i];
        fp += (double)fpe_part[i];
        c  += (double)cnt_part[i];
    }
    #pragma unroll
    for (int off = 32; off > 0; off >>= 1) {
        fn += __shfl_down(fn, off, 64);
        fp += __shfl_down(fp, off, 64);
        c  += __shfl_down(c, off, 64);
    }
    __shared__ double s_fn[16], s_fp[16], s_c[16];
    int wave = threadIdx.x >> 6;
    int lane = threadIdx.x & 63;
    if (lane == 0) { s_fn[wave] = fn; s_fp[wave] = fp; s_c[wave] = c; }
    __syncthreads();

    if (threadIdx.x == 0) {
        double tfn = 0.0, tfp = 0.0, tc = 0.0;
        int nwaves = blockDim.x >> 6;
        for (int w = 0; w < nwaves; ++w) { tfn += s_fn[w]; tfp += s_fp[w]; tc += s_c[w]; }
        double fne_num = tc;
        double fpe_num = (double)n_rows - fne_num;
        double res = 0.0;
        if (fpe_num > 0.0) res += tfp / fpe_num;
        if (fne_num > 0.0) res += tfn / fne_num;
        out[0] = (float)res;
    }
}

extern "C" void kernel_launch(void* const* d_in, const int* in_sizes, int n_in,
                              void* d_out, int out_size, void* d_ws, size_t ws_size,
                              hipStream_t stream) {
    const float4* preds = (const float4*)d_in[0];
    const int* target = (const int*)d_in[1];
    const int* others_idx = (const int*)d_in[2];
    float* out = (float*)d_out;

    int n_rows = in_sizes[0] / 4;   // B = 8388608

    int grid = (n_rows + BLOCK * ROWS - 1) / (BLOCK * ROWS);  // 4096 for B=2^23
    int nparts = grid * (BLOCK / 64);                          // per-wave partials

    // workspace layout: three float arrays of nparts
    float* fne_part = (float*)d_ws;
    float* fpe_part = fne_part + nparts;
    float* cnt_part = fpe_part + nparts;

    mfe_partial<<<grid, BLOCK, 0, stream>>>(preds, target, others_idx,
                                            fne_part, fpe_part, cnt_part, n_rows);
    mfe_final<<<1, 1024, 0, stream>>>(fne_part, fpe_part, cnt_part,
                                      nparts, n_rows, out);
}

// Round 6
// 206.528 us; speedup vs baseline: 1.0846x; 1.0768x over previous
//
#include <hip/hip_runtime.h>

// MFELoss: fused softmax(C=4) + masked-mean reduction to a scalar.
// R6 (= R5 with compile fix): __builtin_nontemporal_load needs a native
// clang vector type, not HIP_vector_type -> use ext_vector_type(4) float.
//  - exact co-resident grid: 512 blocks x 1024 thr = 2 blocks/CU, 32 waves/CU
//  - register double-buffer: prefetch chunk s+1 before computing chunk s
//  - non-temporal loads on both streams (L3-bypass probe)
// ~140 us of reported dur_us is fixed harness restore/poison overhead.

#define BLOCK 1024
#define ROWS 16
#define CHUNK 4
#define STAGES (ROWS / CHUNK)

typedef float vfloat4 __attribute__((ext_vector_type(4)));

__device__ __forceinline__ void mfe_row(vfloat4 x, int t, int o,
                                        float& fne_acc, float& fpe_acc,
                                        float& cnt_acc) {
    float m = fmaxf(fmaxf(x.x, x.y), fmaxf(x.z, x.w));
    float e0 = __expf(x.x - m);
    float e1 = __expf(x.y - m);
    float e2 = __expf(x.z - m);
    float e3 = __expf(x.w - m);
    float S = (e0 + e1) + (e2 + e3);
    float r = 1.0f / S;
    float p0 = e0 * r, p1 = e1 * r, p2 = e2 * r, p3 = e3 * r;
    float s = ((p0 + p1) + p2) + p3;          // ~1.0, computed faithfully
    float po = (o == 0) ? p0 : (o == 1) ? p1 : (o == 2) ? p2 : p3;

    float d1 = s - po;
    float d2 = po - 1.0f;
    float fne_i = 0.5f * (d1 * d1 + d2 * d2);
    float fpe_i = po * po;                    // 0.5*(po^2+po^2)

    bool is_o = (t == o);
    fne_acc += is_o ? fne_i : 0.0f;
    fpe_acc += is_o ? 0.0f : fpe_i;
    cnt_acc += is_o ? 1.0f : 0.0f;            // exact in fp32 at these counts
}

__global__ __launch_bounds__(BLOCK) void mfe_partial(
    const vfloat4* __restrict__ preds,
    const int* __restrict__ target,
    const int* __restrict__ others_idx_p,
    float* __restrict__ fne_part,
    float* __restrict__ fpe_part,
    float* __restrict__ cnt_part,
    int n_rows)
{
    const int o = *others_idx_p;  // wave-uniform scalar
    int tid = blockIdx.x * BLOCK + threadIdx.x;
    int nth = gridDim.x * BLOCK;

    float fne_acc = 0.0f, fpe_acc = 0.0f, cnt_acc = 0.0f;

    if (tid + (ROWS - 1) * nth < n_rows) {
        vfloat4 xbuf[2][CHUNK];
        int     tbuf[2][CHUNK];

        // prologue: fill buffer 0
        #pragma unroll
        for (int k = 0; k < CHUNK; ++k) {
            int i = tid + k * nth;
            xbuf[0][k] = __builtin_nontemporal_load(&preds[i]);
            tbuf[0][k] = __builtin_nontemporal_load(&target[i]);
        }

        #pragma unroll
        for (int s = 0; s < STAGES; ++s) {
            int cur = s & 1;
            int nxt = cur ^ 1;
            // prefetch next chunk before touching current one
            if (s + 1 < STAGES) {
                #pragma unroll
                for (int k = 0; k < CHUNK; ++k) {
                    int i = tid + ((s + 1) * CHUNK + k) * nth;
                    xbuf[nxt][k] = __builtin_nontemporal_load(&preds[i]);
                    tbuf[nxt][k] = __builtin_nontemporal_load(&target[i]);
                }
            }
            // pin prefetch issue before compute
            __builtin_amdgcn_sched_barrier(0);
            #pragma unroll
            for (int k = 0; k < CHUNK; ++k)
                mfe_row(xbuf[cur][k], tbuf[cur][k], o, fne_acc, fpe_acc, cnt_acc);
        }
    } else {
        for (int i = tid; i < n_rows; i += nth)
            mfe_row(preds[i], target[i], o, fne_acc, fpe_acc, cnt_acc);
    }

    // 64-lane wave reduction
    #pragma unroll
    for (int off = 32; off > 0; off >>= 1) {
        fne_acc += __shfl_down(fne_acc, off, 64);
        fpe_acc += __shfl_down(fpe_acc, off, 64);
        cnt_acc += __shfl_down(cnt_acc, off, 64);
    }

    // per-wave partials: no LDS round-trip, no __syncthreads tail
    if ((threadIdx.x & 63) == 0) {
        int part = blockIdx.x * (BLOCK / 64) + (threadIdx.x >> 6);
        fne_part[part] = fne_acc;
        fpe_part[part] = fpe_acc;
        cnt_part[part] = cnt_acc;
    }
}

__global__ __launch_bounds__(1024) void mfe_final(
    const float* __restrict__ fne_part,
    const float* __restrict__ fpe_part,
    const float* __restrict__ cnt_part,
    int nparts, int n_rows, float* __restrict__ out)
{
    double fn = 0.0, fp = 0.0, c = 0.0;
    for (int i = threadIdx.x; i < nparts; i += blockDim.x) {
        fn += (double)fne_part[i];
        fp += (double)fpe_part[i];
        c  += (double)cnt_part[i];
    }
    #pragma unroll
    for (int off = 32; off > 0; off >>= 1) {
        fn += __shfl_down(fn, off, 64);
        fp += __shfl_down(fp, off, 64);
        c  += __shfl_down(c, off, 64);
    }
    __shared__ double s_fn[16], s_fp[16], s_c[16];
    int wave = threadIdx.x >> 6;
    int lane = threadIdx.x & 63;
    if (lane == 0) { s_fn[wave] = fn; s_fp[wave] = fp; s_c[wave] = c; }
    __syncthreads();

    if (threadIdx.x == 0) {
        double tfn = 0.0, tfp = 0.0, tc = 0.0;
        int nwaves = blockDim.x >> 6;
        for (int w = 0; w < nwaves; ++w) { tfn += s_fn[w]; tfp += s_fp[w]; tc += s_c[w]; }
        double fne_num = tc;
        double fpe_num = (double)n_rows - fne_num;
        double res = 0.0;
        if (fpe_num > 0.0) res += tfp / fpe_num;
        if (fne_num > 0.0) res += tfn / fne_num;
        out[0] = (float)res;
    }
}

extern "C" void kernel_launch(void* const* d_in, const int* in_sizes, int n_in,
                              void* d_out, int out_size, void* d_ws, size_t ws_size,
                              hipStream_t stream) {
    const vfloat4* preds = (const vfloat4*)d_in[0];
    const int* target = (const int*)d_in[1];
    const int* others_idx = (const int*)d_in[2];
    float* out = (float*)d_out;

    int n_rows = in_sizes[0] / 4;   // B = 8388608

    int grid = (n_rows + BLOCK * ROWS - 1) / (BLOCK * ROWS);  // 512 for B=2^23
    int nparts = grid * (BLOCK / 64);                          // 8192 per-wave partials

    float* fne_part = (float*)d_ws;
    float* fpe_part = fne_part + nparts;
    float* cnt_part = fpe_part + nparts;

    mfe_partial<<<grid, BLOCK, 0, stream>>>(preds, target, others_idx,
                                            fne_part, fpe_part, cnt_part, n_rows);
    mfe_final<<<1, 1024, 0, stream>>>(fne_part, fpe_part, cnt_part,
                                      nparts, n_rows, out);
}